// Round 2
// baseline (2295.071 us; speedup 1.0000x reference)
//
#include <hip/hip_runtime.h>
#include <hip/hip_bf16.h>
#include <hip/hip_cooperative_groups.h>
#include <stdint.h>

namespace cg = cooperative_groups;

// Binarized MLP: B=8192, D_IN=3072, H=2000 (pad 2048), C=10.
// L1 (exact, bf16 MFMA): Q=round(x*2^14)=d1*512+d0 digits exact in bf16;
//   K=6144 GEMM [d1*512|d0]@[s|s]^T -> Ti exact; residual K=3072 GEMM fuses
//   z1 = mean|W1|*2^-14*(Ti+Sr)+b1 in double.
// Layers 2-4: i8 MFMA on {0,1}x{+-1} — exact i32, BK=128. h4 in bf16.
// R7: single cooperative mega-kernel. R3-R6 showed ~20-25us per graph-node
// boundary (R6: 12->8 nodes bought ~80us). All GEMM phases already run at
// grid 1024x256 with __launch_bounds__(256,4) => exactly 4 blocks/CU x 256 CU
// co-resident, so the whole pipeline fits one cooperative launch with
// cg::grid sync between layers (~2-5us each). GEMM/epilogue numerics are
// bit-identical to the passing R6. Fallback to the R6 8-node path if the
// cooperative launch is rejected under graph capture.
typedef __bf16 bf16_t;
typedef __attribute__((ext_vector_type(8))) __bf16 bf16x8;
typedef __attribute__((ext_vector_type(4))) float f32x4;
typedef __attribute__((ext_vector_type(4))) int i32x4;
typedef __attribute__((ext_vector_type(8))) char i8x8;

#define GLD_LDS16(g, l) __builtin_amdgcn_global_load_lds( \
    (__attribute__((address_space(1))) void*)(g), \
    (__attribute__((address_space(3))) void*)(l), 16, 0, 0)

__device__ __forceinline__ void block_reduce_atomic_d(double v, double* dst) {
    #pragma unroll
    for (int off = 32; off > 0; off >>= 1) v += __shfl_down(v, off);
    __shared__ double rb[4];
    const int t = threadIdx.x;
    __syncthreads();                      // rb reuse guard (called repeatedly in mega)
    if ((t & 63) == 0) rb[t >> 6] = v;
    __syncthreads();
    if (t == 0) atomicAdd(dst, rb[0] + rb[1] + rb[2] + rb[3]);
}

// --- prep row bodies (return per-thread partial |W| sums) ---
__device__ __forceinline__ double prep_w1_row(
    const float* __restrict__ W, int r, bf16_t* __restrict__ S)
{
    const int t = threadIdx.x;
    double sl = 0.0;
    for (int cb = t * 8; cb < 3072; cb += 2048) {
        bf16x8 o;
        if (r < 2000) {
            #pragma unroll
            for (int j = 0; j < 8; ++j) {
                float v = W[(size_t)r * 3072 + cb + j];
                sl += (double)fabsf(v);
                o[j] = (bf16_t)(v > 0.f ? 1.f : (v < 0.f ? -1.f : 0.f));
            }
        } else {
            #pragma unroll
            for (int j = 0; j < 8; ++j) o[j] = (bf16_t)0.f;
        }
        *(bf16x8*)&S[(size_t)r * 6144 + cb] = o;
        *(bf16x8*)&S[(size_t)r * 6144 + 3072 + cb] = o;
    }
    return sl;
}

__device__ __forceinline__ double prep_wi8_row(
    const float* __restrict__ W, int r, int8_t* __restrict__ S)
{
    const int t = threadIdx.x;
    const int cb = t * 8;
    double sl = 0.0;
    i8x8 o;
    if (r < 2000) {
        #pragma unroll
        for (int j = 0; j < 8; ++j) {
            int c = cb + j;
            float v = (c < 2000) ? W[(size_t)r * 2000 + c] : 0.f;
            sl += (double)fabsf(v);
            o[j] = (char)(v > 0.f ? 1 : (v < 0.f ? -1 : 0));
        }
    } else {
        #pragma unroll
        for (int j = 0; j < 8; ++j) o[j] = 0;
    }
    *(i8x8*)&S[(size_t)r * 2048 + cb] = o;
    return sl;
}

__device__ __forceinline__ void prep_x_row(
    const float* __restrict__ x, int r, bf16_t* __restrict__ XLi, bf16_t* __restrict__ XLr)
{
    const int t = threadIdx.x;
    for (int cb = t * 8; cb < 3072; cb += 2048) {
        float4 v0 = *(const float4*)&x[(size_t)r * 3072 + cb];
        float4 v1 = *(const float4*)&x[(size_t)r * 3072 + cb + 4];
        float xv[8] = {v0.x, v0.y, v0.z, v0.w, v1.x, v1.y, v1.z, v1.w};
        bf16x8 hi, lo, re;
        #pragma unroll
        for (int j = 0; j < 8; ++j) {
            int Q = (int)lrintf(xv[j] * 16384.f);           // x * 2^14
            int d0 = ((Q + 256) & 511) - 256;               // [-256,255], exact bf16
            int d1 = (Q - d0) / 512;                        // |d1|<=~182, exact bf16
            float rr = xv[j] - (float)Q * (1.f / 16384.f);  // exact (Sterbenz)
            hi[j] = (bf16_t)(float)(d1 * 512);              // exact (pow2 shift)
            lo[j] = (bf16_t)(float)d0;
            re[j] = (bf16_t)(rr * 16384.f);                 // in [-.5,.5]
        }
        *(bf16x8*)&XLi[(size_t)r * 6144 + cb]        = hi;
        *(bf16x8*)&XLi[(size_t)r * 6144 + 3072 + cb] = lo;
        *(bf16x8*)&XLr[(size_t)r * 3072 + cb]        = re;
    }
}

// --- bf16 GEMM phase: C = A @ B^T, 128x128x64 tiles, flattened 1024-block grid.
// rawOut mode writes fp32 acc. Else epilogue (double):
// z = sumW*invDivW*extraScale*(acc+addPlane?) + bias; binOut i8 {0,1};
// atomic double sum(relu z). Bit-identical to R6's gemm_bin.
__device__ void gemm_bin_phase(
    bf16_t* sA, bf16_t* sB,
    const bf16_t* __restrict__ A, const bf16_t* __restrict__ B, int K, int ldB,
    float* __restrict__ rawOut,
    const float* __restrict__ addPlane,
    const double* __restrict__ sumW, double invDivW, double extraScale,
    const float* __restrict__ bias,
    int8_t* __restrict__ binOut,
    double* __restrict__ habs)
{
    const int t = threadIdx.x;
    const int lane = t & 63;
    const int wave = t >> 6;
    const int wr = wave >> 1, wc = wave & 1;
    const int qa = lane >> 4, rA = lane & 15;
    const int blk = (int)blockIdx.x;
    const size_t bm = (size_t)(blk >> 4) * 128, bn = (size_t)(blk & 15) * 128;

    f32x4 acc[4][4] = {};

    const bf16_t* Abase = A + bm * (size_t)K;
    const bf16_t* Bbase = B + bn * (size_t)ldB;

    const int swz = rA & 7;
    const int offk0 = ((0 + qa) ^ swz) * 8;
    const int offk1 = ((4 + qa) ^ swz) * 8;
    const int arow = wr * 64 + rA;
    const int brow = wc * 64 + rA;

    for (int k0 = 0; k0 < K; k0 += 64) {
        #pragma unroll
        for (int i = 0; i < 4; ++i) {
            int c = i * 256 + t;
            int row = c >> 3, cc = c & 7;
            int ccg = cc ^ (row & 7);
            GLD_LDS16(Abase + (size_t)row * K + k0 + ccg * 8, &sA[c * 8]);
        }
        #pragma unroll
        for (int i = 0; i < 4; ++i) {
            int c = i * 256 + t;
            int row = c >> 3, cc = c & 7;
            int ccg = cc ^ (row & 7);
            GLD_LDS16(Bbase + (size_t)row * ldB + k0 + ccg * 8, &sB[c * 8]);
        }
        __syncthreads();

        bf16x8 fa[4][2], fb[4][2];
        #pragma unroll
        for (int i = 0; i < 4; ++i) {
            fa[i][0] = *(const bf16x8*)&sA[(arow + i * 16) * 64 + offk0];
            fa[i][1] = *(const bf16x8*)&sA[(arow + i * 16) * 64 + offk1];
            fb[i][0] = *(const bf16x8*)&sB[(brow + i * 16) * 64 + offk0];
            fb[i][1] = *(const bf16x8*)&sB[(brow + i * 16) * 64 + offk1];
        }
        #pragma unroll
        for (int i = 0; i < 4; ++i)
            #pragma unroll
            for (int j = 0; j < 4; ++j) {
                acc[i][j] = __builtin_amdgcn_mfma_f32_16x16x32_bf16(fa[i][0], fb[j][0], acc[i][j], 0, 0, 0);
                acc[i][j] = __builtin_amdgcn_mfma_f32_16x16x32_bf16(fa[i][1], fb[j][1], acc[i][j], 0, 0, 0);
            }
        __syncthreads();
    }

    if (rawOut) {   // exact integer partial sums in fp32
        #pragma unroll
        for (int i = 0; i < 4; ++i)
            #pragma unroll
            for (int j = 0; j < 4; ++j)
                #pragma unroll
                for (int rr = 0; rr < 4; ++rr) {
                    int m = (int)bm + wr * 64 + i * 16 + qa * 4 + rr;
                    int n = (int)bn + wc * 64 + j * 16 + rA;
                    rawOut[(size_t)m * 2048 + n] = acc[i][j][rr];
                }
        return;
    }

    const double scale = sumW[0] * invDivW * extraScale;
    double hs = 0.0;
    #pragma unroll
    for (int i = 0; i < 4; ++i) {
        #pragma unroll
        for (int j = 0; j < 4; ++j) {
            #pragma unroll
            for (int rr = 0; rr < 4; ++rr) {
                // C/D layout: col = lane&15, row = (lane>>4)*4 + reg
                int m = (int)bm + wr * 64 + i * 16 + qa * 4 + rr;
                int n = (int)bn + wc * 64 + j * 16 + rA;
                size_t idx = (size_t)m * 2048 + n;
                double s = (double)acc[i][j][rr];
                if (addPlane) s += (double)addPlane[idx];
                double z = s * scale + (n < 2000 ? (double)bias[n] : -1.0);
                binOut[idx] = (int8_t)(z > 0.0 ? 1 : 0);
                if (n < 2000 && z > 0.0) hs += z;
            }
        }
    }
    if (habs) block_reduce_atomic_d(hs, habs);
}

// --- i8 GEMM phase: A:[8192][2048] {0,1}, B:[2048][2048] {+-1,0}.
// 128x128 tile, BK=128, XOR-swizzled 16B chunks. Bit-identical to R6's gemm_i8.
__device__ void gemm_i8_phase(
    int8_t* sA, int8_t* sB,
    const int8_t* __restrict__ A, const int8_t* __restrict__ B,
    const double* __restrict__ sumW, double invDivW,
    const double* __restrict__ sumH, double invDivH,
    const float* __restrict__ bias,
    int8_t* __restrict__ binOut, bf16_t* __restrict__ hOut,
    double* __restrict__ habs)
{
    const int K = 2048;                           // bytes per row
    const int t = threadIdx.x;
    const int lane = t & 63;
    const int wave = t >> 6;
    const int wr = wave >> 1, wc = wave & 1;
    const int qa = lane >> 4, rA = lane & 15;
    const int blk = (int)blockIdx.x;
    const size_t bm = (size_t)(blk >> 4) * 128, bn = (size_t)(blk & 15) * 128;

    i32x4 acc[4][4] = {};

    const int8_t* Abase = A + bm * (size_t)K;
    const int8_t* Bbase = B + bn * (size_t)K;

    const int swz = rA & 7;
    const int offb0 = ((0 + qa) ^ swz) * 16;      // k-half 0: k in [0,64)
    const int offb1 = ((4 + qa) ^ swz) * 16;      // k-half 1: k in [64,128)
    const int arow = wr * 64 + rA;
    const int brow = wc * 64 + rA;

    for (int k0 = 0; k0 < K; k0 += 128) {
        #pragma unroll
        for (int i = 0; i < 4; ++i) {
            int c = i * 256 + t;
            int row = c >> 3, cc = c & 7;
            int ccg = cc ^ (row & 7);
            GLD_LDS16(Abase + (size_t)row * K + k0 + ccg * 16, &sA[c * 16]);
        }
        #pragma unroll
        for (int i = 0; i < 4; ++i) {
            int c = i * 256 + t;
            int row = c >> 3, cc = c & 7;
            int ccg = cc ^ (row & 7);
            GLD_LDS16(Bbase + (size_t)row * K + k0 + ccg * 16, &sB[c * 16]);
        }
        __syncthreads();

        {   // k-half 0
            i32x4 fa[4], fb[4];
            #pragma unroll
            for (int i = 0; i < 4; ++i) {
                fa[i] = *(const i32x4*)&sA[(arow + i * 16) * 128 + offb0];
                fb[i] = *(const i32x4*)&sB[(brow + i * 16) * 128 + offb0];
            }
            #pragma unroll
            for (int i = 0; i < 4; ++i)
                #pragma unroll
                for (int j = 0; j < 4; ++j)
                    acc[i][j] = __builtin_amdgcn_mfma_i32_16x16x64_i8(fa[i], fb[j], acc[i][j], 0, 0, 0);
        }
        {   // k-half 1
            i32x4 fa[4], fb[4];
            #pragma unroll
            for (int i = 0; i < 4; ++i) {
                fa[i] = *(const i32x4*)&sA[(arow + i * 16) * 128 + offb1];
                fb[i] = *(const i32x4*)&sB[(brow + i * 16) * 128 + offb1];
            }
            #pragma unroll
            for (int i = 0; i < 4; ++i)
                #pragma unroll
                for (int j = 0; j < 4; ++j)
                    acc[i][j] = __builtin_amdgcn_mfma_i32_16x16x64_i8(fa[i], fb[j], acc[i][j], 0, 0, 0);
        }
        __syncthreads();
    }

    const double scale = sumW[0] * invDivW * sumH[0] * invDivH;
    double hs = 0.0;
    #pragma unroll
    for (int i = 0; i < 4; ++i) {
        #pragma unroll
        for (int j = 0; j < 4; ++j) {
            #pragma unroll
            for (int rr = 0; rr < 4; ++rr) {
                int m = (int)bm + wr * 64 + i * 16 + qa * 4 + rr;
                int n = (int)bn + wc * 64 + j * 16 + rA;
                size_t idx = (size_t)m * 2048 + n;
                double z = (double)acc[i][j][rr] * scale +
                           (n < 2000 ? (double)bias[n] : -1.0);
                if (binOut) binOut[idx] = (int8_t)(z > 0.0 ? 1 : 0);
                if (hOut)   hOut[idx] = (bf16_t)(float)(z > 0.0 ? z : 0.0);
                if (n < 2000 && z > 0.0) hs += z;
            }
        }
    }
    if (habs) block_reduce_atomic_d(hs, habs);
}

// one row of: out[r][:] = h4[r, :2000] @ W5.T + b5
__device__ __forceinline__ void fc_row(
    const bf16_t* __restrict__ h4, const float* __restrict__ W5,
    const float* __restrict__ b5, float* __restrict__ out, int r)
{
    const int t = threadIdx.x;
    float acc[10] = {};
    for (int k = t; k < 2000; k += 256) {
        float a = (float)h4[(size_t)r * 2048 + k];
        #pragma unroll
        for (int c = 0; c < 10; ++c) acc[c] += a * W5[c * 2000 + k];
    }
    __shared__ float red[4][10];
    #pragma unroll
    for (int c = 0; c < 10; ++c) {
        float v = acc[c];
        #pragma unroll
        for (int off = 32; off > 0; off >>= 1) v += __shfl_down(v, off);
        if ((t & 63) == 0) red[t >> 6][c] = v;
    }
    __syncthreads();
    if (t < 10) out[(size_t)r * 10 + t] = red[0][t] + red[1][t] + red[2][t] + red[3][t] + b5[t];
    __syncthreads();                      // red reuse guard (looped call in mega)
}

// ================= cooperative mega-kernel: whole pipeline, 1 dispatch ======
// grid 1024 x 256 @ (256,4): 4 blocks/CU x 256 CU = exactly co-resident.
// LDS: 32KiB tile union + ~200B reducers => 4 blocks/CU fits 160KiB.
__global__ __launch_bounds__(256, 4) void mega(
    const float* x,
    const float* W1, const float* W2, const float* W3, const float* W4,
    const float* W5,
    const float* b1, const float* b2, const float* b3, const float* b4,
    const float* b5,
    bf16_t* sW1, int8_t* sW2, int8_t* sW3, int8_t* sW4,
    bf16_t* XLi, bf16_t* XLr, float* Ti, double* scD,
    int8_t* p0, int8_t* p1, bf16_t* h4, float* out)
{
    __shared__ __align__(16) char smem[32768];
    cg::grid_group grid = cg::this_grid();
    const int blk = (int)blockIdx.x;

    // ---- phase P: prep (1024 blocks x 16 row-units; same per-row math) ----
    {
        double s1 = prep_w1_row(W1, blk, sW1) + prep_w1_row(W1, blk + 1024, sW1);
        double s2 = prep_wi8_row(W2, blk, sW2) + prep_wi8_row(W2, blk + 1024, sW2);
        double s3 = prep_wi8_row(W3, blk, sW3) + prep_wi8_row(W3, blk + 1024, sW3);
        double s4 = prep_wi8_row(W4, blk, sW4) + prep_wi8_row(W4, blk + 1024, sW4);
        #pragma unroll 1
        for (int u = 0; u < 8; ++u) prep_x_row(x, u * 1024 + blk, XLi, XLr);
        block_reduce_atomic_d(s1, scD + 0);
        block_reduce_atomic_d(s2, scD + 1);
        block_reduce_atomic_d(s3, scD + 2);
        block_reduce_atomic_d(s4, scD + 3);
    }
    __threadfence(); grid.sync();

    bf16_t* sA16 = (bf16_t*)smem;  bf16_t* sB16 = (bf16_t*)(smem + 16384);
    int8_t* sA8  = (int8_t*)smem;  int8_t* sB8  = (int8_t*)(smem + 16384);

    // ---- L1a: Ti = XLi @ sW1^T (K=6144), raw fp32 (exact ints) ----
    gemm_bin_phase(sA16, sB16, XLi, sW1, 6144, 6144, Ti, nullptr,
                   nullptr, 0.0, 1.0, nullptr, nullptr, nullptr);
    __syncthreads();
    // ---- L1b: residual GEMM + combine (Ti read is same-thread, no grid sync) ----
    gemm_bin_phase(sA16, sB16, XLr, sW1, 3072, 6144, nullptr, Ti,
                   scD + 0, 1.0 / 6144000.0, 1.0 / 16384.0, b1, p0, scD + 4);
    __threadfence(); grid.sync();
    // ---- layers 2-4 (i8). p1 aliases XLi (dead), h4 aliases Ti (dead). ----
    gemm_i8_phase(sA8, sB8, p0, sW2, scD + 1, 1.0 / 4000000.0,
                  scD + 4, 1.0 / 16384000.0, b2, p1, nullptr, scD + 5);
    __threadfence(); grid.sync();
    gemm_i8_phase(sA8, sB8, p1, sW3, scD + 2, 1.0 / 4000000.0,
                  scD + 5, 1.0 / 16384000.0, b3, p0, nullptr, scD + 6);
    __threadfence(); grid.sync();
    gemm_i8_phase(sA8, sB8, p0, sW4, scD + 3, 1.0 / 4000000.0,
                  scD + 6, 1.0 / 16384000.0, b4, nullptr, h4, nullptr);
    __threadfence(); grid.sync();
    // ---- fc: out = h4[:, :2000] @ W5^T + b5 (8 rows per block) ----
    #pragma unroll 1
    for (int i = 0; i < 8; ++i) fc_row(h4, W5, b5, out, blk * 8 + i);
}

// ================= fallback wrappers (R6 8-node path, bit-identical) ========
__global__ __launch_bounds__(256) void k_prep(
    const float* __restrict__ W1, const float* __restrict__ W2,
    const float* __restrict__ W3, const float* __restrict__ W4,
    const float* __restrict__ x,
    bf16_t* __restrict__ sW1, int8_t* __restrict__ sW2,
    int8_t* __restrict__ sW3, int8_t* __restrict__ sW4,
    bf16_t* __restrict__ XLi, bf16_t* __restrict__ XLr,
    double* __restrict__ scD)
{
    const int g = blockIdx.x;
    if      (g < 2048)  block_reduce_atomic_d(prep_w1_row(W1, g, sW1), scD + 0);
    else if (g < 4096)  block_reduce_atomic_d(prep_wi8_row(W2, g - 2048, sW2), scD + 1);
    else if (g < 6144)  block_reduce_atomic_d(prep_wi8_row(W3, g - 4096, sW3), scD + 2);
    else if (g < 8192)  block_reduce_atomic_d(prep_wi8_row(W4, g - 6144, sW4), scD + 3);
    else                prep_x_row(x, g - 8192, XLi, XLr);
}

__global__ __launch_bounds__(256, 4) void k_gemm_bin(
    const bf16_t* A, const bf16_t* B, int K, int ldB,
    float* rawOut, const float* addPlane,
    const double* sumW, double invDivW, double extraScale,
    const float* bias, int8_t* binOut, double* habs)
{
    __shared__ __align__(16) char smem[32768];
    gemm_bin_phase((bf16_t*)smem, (bf16_t*)(smem + 16384), A, B, K, ldB,
                   rawOut, addPlane, sumW, invDivW, extraScale, bias, binOut, habs);
}

__global__ __launch_bounds__(256, 4) void k_gemm_i8(
    const int8_t* A, const int8_t* B,
    const double* sumW, double invDivW,
    const double* sumH, double invDivH,
    const float* bias, int8_t* binOut, bf16_t* hOut, double* habs)
{
    __shared__ __align__(16) char smem[32768];
    gemm_i8_phase((int8_t*)smem, (int8_t*)(smem + 16384), A, B,
                  sumW, invDivW, sumH, invDivH, bias, binOut, hOut, habs);
}

__global__ __launch_bounds__(256) void k_fc(
    const bf16_t* h4, const float* W5, const float* b5, float* out)
{
    fc_row(h4, W5, b5, out, (int)blockIdx.x);
}

extern "C" void kernel_launch(void* const* d_in, const int* in_sizes, int n_in,
                              void* d_out, int out_size, void* d_ws, size_t ws_size,
                              hipStream_t stream)
{
    const float* x  = (const float*)d_in[0];
    const float* W1 = (const float*)d_in[1];
    const float* b1 = (const float*)d_in[2];
    const float* W2 = (const float*)d_in[3];
    const float* b2 = (const float*)d_in[4];
    const float* W3 = (const float*)d_in[5];
    const float* b3 = (const float*)d_in[6];
    const float* W4 = (const float*)d_in[7];
    const float* b4 = (const float*)d_in[8];
    const float* W5 = (const float*)d_in[9];
    const float* b5 = (const float*)d_in[10];
    float* out = (float*)d_out;
    (void)ws_size; (void)in_sizes; (void)n_in; (void)out_size;

    const size_t PH = (size_t)8192 * 2048;

    // Workspace layout unchanged from R6 (260.3 MiB total; 264 proven safe)
    char* w = (char*)d_ws;
    double* scD = (double*)w;                     // [0..3]=sum|W1..4|, [4..6]=sum h1..3
    size_t off = 256;
    bf16_t* XLi = (bf16_t*)(w + off); off += (size_t)8192 * 6144 * 2;  // 96 MiB
    bf16_t* XLr = (bf16_t*)(w + off); off += (size_t)8192 * 3072 * 2;  // 48 MiB
    bf16_t* sW1 = (bf16_t*)(w + off); off += (size_t)2048 * 6144 * 2;  // 24 MiB [s|s]
    float*  Ti  = (float*)(w + off);  off += PH * 4;                   // 64 MiB
    int8_t* p0  = (int8_t*)(w + off); off += PH;                       // 16 MiB
    int8_t* sW2 = (int8_t*)(w + off); off += (size_t)2048 * 2048;      // 4 MiB
    int8_t* sW3 = (int8_t*)(w + off); off += (size_t)2048 * 2048;      // 4 MiB
    int8_t* sW4 = (int8_t*)(w + off); off += (size_t)2048 * 2048;      // 4 MiB
    int8_t* p1  = (int8_t*)XLi;                    // XLi dead after L1 GEMMs
    bf16_t* h4  = (bf16_t*)Ti;                     // Ti dead after L1res epilogue

    hipMemsetAsync(w, 0, 256, stream);

    void* kargs[] = {
        (void*)&x, (void*)&W1, (void*)&W2, (void*)&W3, (void*)&W4, (void*)&W5,
        (void*)&b1, (void*)&b2, (void*)&b3, (void*)&b4, (void*)&b5,
        (void*)&sW1, (void*)&sW2, (void*)&sW3, (void*)&sW4,
        (void*)&XLi, (void*)&XLr, (void*)&Ti, (void*)&scD,
        (void*)&p0, (void*)&p1, (void*)&h4, (void*)&out
    };
    hipError_t cerr = hipLaunchCooperativeKernel(
        reinterpret_cast<void*>(mega), dim3(1024), dim3(256), kargs, 0, stream);

    if (cerr != hipSuccess) {
        // R6 fallback: 8-node path, bit-identical numerics.
        k_prep<<<16384, 256, 0, stream>>>(W1, W2, W3, W4, x,
                                          sW1, sW2, sW3, sW4, XLi, XLr, scD);
        k_gemm_bin<<<1024, 256, 0, stream>>>(XLi, sW1, 6144, 6144, Ti, nullptr,
                                             nullptr, 0.0, 1.0, nullptr, nullptr, nullptr);
        k_gemm_bin<<<1024, 256, 0, stream>>>(XLr, sW1, 3072, 6144, nullptr, Ti,
                                             scD + 0, 1.0 / 6144000.0, 1.0 / 16384.0,
                                             b1, p0, scD + 4);
        k_gemm_i8<<<1024, 256, 0, stream>>>(p0, sW2,
                                            scD + 1, 1.0 / 4000000.0, scD + 4, 1.0 / 16384000.0,
                                            b2, p1, nullptr, scD + 5);
        k_gemm_i8<<<1024, 256, 0, stream>>>(p1, sW3,
                                            scD + 2, 1.0 / 4000000.0, scD + 5, 1.0 / 16384000.0,
                                            b3, p0, nullptr, scD + 6);
        k_gemm_i8<<<1024, 256, 0, stream>>>(p0, sW4,
                                            scD + 3, 1.0 / 4000000.0, scD + 6, 1.0 / 16384000.0,
                                            b4, nullptr, h4, nullptr);
        k_fc<<<8192, 256, 0, stream>>>(h4, W5, b5, out);
    }
}